// Round 1
// baseline (651.425 us; speedup 1.0000x reference)
//
#include <hip/hip_runtime.h>
#include <cstdint>
#include <cstddef>

static constexpr int Gn = 2;
static constexpr int Tn = 4096;
static constexpr int Hn = 2048;
static constexpr int En = 64;
static constexpr int CAPn = 128;
static constexpr size_t GT = (size_t)Gn * Tn;          // 8192
static constexpr size_t GTEC = GT * En * CAPn;         // 67,108,864

// ---------------------------------------------------------------------------
// Wave-level (64 lanes = 64 experts) softmax + top-2 + z-loss term, all f64.
// Tie-breaking on equal probs: lower expert index wins (matches lax.top_k).
// ---------------------------------------------------------------------------
__device__ inline void wave_softmax_topk(
    double logit, int g, int t,
    double* __restrict__ dkey, double* __restrict__ dlogz2,
    float* __restrict__ probs,
    int* __restrict__ idx0, int* __restrict__ idx1,
    float* __restrict__ g0f, float* __restrict__ g1f)
{
  const int e = threadIdx.x & 63;
  double m = logit;
  #pragma unroll
  for (int off = 32; off; off >>= 1) {
    double o = __shfl_xor(m, off);
    m = o > m ? o : m;
  }
  double ex = exp(logit - m);
  double s = ex;
  #pragma unroll
  for (int off = 32; off; off >>= 1) s += __shfl_xor(s, off);
  double p = ex / s;
  size_t gt = (size_t)g * Tn + t;
  probs[gt * En + e] = (float)p;

  // top-1 (value, index) with lower-index tie-break
  double bp = p; int bi = e;
  #pragma unroll
  for (int off = 32; off; off >>= 1) {
    double op = __shfl_xor(bp, off);
    int    oi = __shfl_xor(bi, off);
    if (op > bp || (op == bp && oi < bi)) { bp = op; bi = oi; }
  }
  // top-2: mask out top-1 lane
  double q = (e == bi) ? -1.0 : p;
  double bp2 = q; int bi2 = e;
  #pragma unroll
  for (int off = 32; off; off >>= 1) {
    double op = __shfl_xor(bp2, off);
    int    oi = __shfl_xor(bi2, off);
    if (op > bp2 || (op == bp2 && oi < bi2)) { bp2 = op; bi2 = oi; }
  }
  if (e == 0) {
    dkey[gt] = bp;                       // sort key = top-1 gate (f64)
    double lz = m + log(s);              // logsumexp
    dlogz2[gt] = lz * lz;
    idx0[gt] = bi;  idx1[gt] = bi2;
    g0f[gt] = (float)bp;  g1f[gt] = (float)bp2;
  }
}

// ---------------------------------------------------------------------------
// k1: logits (f64 accumulation) + softmax + top2. 8 tokens/block, 256 thr.
// wave w handles tokens (t0+w) and (t0+w+4); lane = expert.
// ---------------------------------------------------------------------------
__global__ __launch_bounds__(256) void k1_gemm(
    const float* __restrict__ X, const float* __restrict__ W,
    const float* __restrict__ Bv,
    double* __restrict__ dkey, double* __restrict__ dlogz2,
    float* __restrict__ probs,
    int* __restrict__ idx0, int* __restrict__ idx1,
    float* __restrict__ g0f, float* __restrict__ g1f)
{
  __shared__ float xs[8 * Hn];                     // 64 KB
  const int tid = threadIdx.x;
  const int bid = blockIdx.x;
  const int g  = bid >> 9;                         // 512 blocks per group
  const int t0 = (bid & 511) * 8;
  const size_t base = ((size_t)g * Tn + t0) * Hn;
  const float4* Xv = (const float4*)(X + base);
  float4* xsv = (float4*)xs;
  #pragma unroll
  for (int i = 0; i < 16; ++i) xsv[tid + 256 * i] = Xv[tid + 256 * i];
  __syncthreads();

  const int e  = tid & 63;
  const int tk = tid >> 6;
  const float* x0 = xs + tk * Hn;
  const float* x1 = xs + (tk + 4) * Hn;
  const float* wp = W + e;
  double a0 = 0.0, a1 = 0.0;
  #pragma unroll 4
  for (int h = 0; h < Hn; ++h) {
    double w = (double)wp[(size_t)h * En];
    a0 += (double)x0[h] * w;
    a1 += (double)x1[h] * w;
  }
  double b = (double)Bv[e];
  a0 += b; a1 += b;

  wave_softmax_topk(a0, g, t0 + tk,     dkey, dlogz2, probs, idx0, idx1, g0f, g1f);
  wave_softmax_topk(a1, g, t0 + tk + 4, dkey, dlogz2, probs, idx0, idx1, g0f, g1f);
}

// ---------------------------------------------------------------------------
// k2: stable descending rank (== argsort(-gate0, stable)). O(T^2) compares,
// keys broadcast from LDS. Scatters perm + expert ids into sorted order.
// ---------------------------------------------------------------------------
__global__ __launch_bounds__(256) void k2_rank(
    const double* __restrict__ dkey,
    const int* __restrict__ idx0, const int* __restrict__ idx1,
    int* __restrict__ perm, int* __restrict__ sidx0, int* __restrict__ sidx1)
{
  __shared__ double keys[Tn];                      // 32 KB
  const int tid = threadIdx.x;
  const int bid = blockIdx.x;
  const int g = bid >> 4;                          // 16 blocks per group
  const int part = bid & 15;
  const size_t gbase = (size_t)g * Tn;
  for (int i = tid; i < Tn; i += 256) keys[i] = dkey[gbase + i];
  __syncthreads();

  const int tg = part * 256 + tid;
  const double k = keys[tg];
  int r = 0;
  for (int j = 0; j < Tn; ++j) {
    double kj = keys[j];
    r += (kj > k) || (kj == k && j < tg);          // stable, descending
  }
  perm[gbase + r]  = tg;
  sidx0[gbase + r] = idx0[gbase + tg];
  sidx1[gbase + r] = idx1[gbase + tg];
}

// ---------------------------------------------------------------------------
// k3: exact cumsum priorities. One wave per (g,e); scan sorted k=0 stream,
// then k=1 stream (flat order k*T + p), via ballot + popcount prefix.
// ---------------------------------------------------------------------------
__global__ __launch_bounds__(256) void k3_prio(
    const int* __restrict__ sidx0, const int* __restrict__ sidx1,
    const int* __restrict__ perm,
    int* __restrict__ prio0, int* __restrict__ prio1, int* __restrict__ cntge)
{
  const int tid  = threadIdx.x;
  const int wid  = (blockIdx.x * 256 + tid) >> 6;  // 0..127 = (g,e)
  const int lane = tid & 63;
  const int g = wid >> 6, e = wid & 63;
  const size_t gbase = (size_t)g * Tn;
  int cnt = 0;
  for (int step = 0; step < Tn / 64; ++step) {
    int p = step * 64 + lane;
    bool mt = (sidx0[gbase + p] == e);
    unsigned long long mask = __ballot(mt);
    int pr = cnt + __popcll(mask & ((1ull << lane) - 1ull));
    if (mt) prio0[gbase + perm[gbase + p]] = pr;
    cnt += __popcll(mask);
  }
  for (int step = 0; step < Tn / 64; ++step) {
    int p = step * 64 + lane;
    bool mt = (sidx1[gbase + p] == e);
    unsigned long long mask = __ballot(mt);
    int pr = cnt + __popcll(mask & ((1ull << lane) - 1ull));
    if (mt) prio1[gbase + perm[gbase + p]] = pr;
    cnt += __popcll(mask);
  }
  if (lane == 0) cntge[g * En + e] = cnt;          // tokens routed to (g,e)
}

// ---------------------------------------------------------------------------
// k4: per-(g,e) probability sums (deterministic: fixed lane strides + tree).
// ---------------------------------------------------------------------------
__global__ __launch_bounds__(256) void k4_sumprob(
    const float* __restrict__ probs, double* __restrict__ sumprob)
{
  const int tid  = threadIdx.x;
  const int wid  = (blockIdx.x * 256 + tid) >> 6;
  const int lane = tid & 63;
  const int g = wid >> 6, e = wid & 63;
  double s = 0.0;
  for (int i = 0; i < Tn / 64; ++i) {
    int t = i * 64 + lane;
    s += (double)probs[((size_t)g * Tn + t) * En + e];
  }
  #pragma unroll
  for (int off = 32; off; off >>= 1) s += __shfl_xor(s, off);
  if (lane == 0) sumprob[g * En + e] = s;
}

// ---------------------------------------------------------------------------
// k5: scalar losses (deterministic LDS tree reductions).
// ---------------------------------------------------------------------------
__global__ __launch_bounds__(256) void k5_scalars(
    const double* __restrict__ dlogz2, const double* __restrict__ sumprob,
    const int* __restrict__ cntge, float* __restrict__ out)
{
  __shared__ double red[256];
  const int tid = threadIdx.x;
  double z = 0.0;
  for (int i = tid; i < (int)GT; i += 256) z += dlogz2[i];
  red[tid] = z; __syncthreads();
  for (int s = 128; s; s >>= 1) { if (tid < s) red[tid] += red[tid + s]; __syncthreads(); }
  double zloss = red[0] / (double)GT;
  __syncthreads();

  double a = 0.0;
  if (tid < Gn * En) a = (double)cntge[tid] * sumprob[tid];
  red[tid] = a; __syncthreads();
  for (int s = 128; s; s >>= 1) { if (tid < s) red[tid] += red[tid + s]; __syncthreads(); }
  if (tid == 0) {
    // mean_{g,e}((cnt/T)*(sp/T)) * E^2  =  sum(cnt*sp) * E / (G*T*T)
    double aux = red[0] * (double)En / ((double)Gn * (double)Tn * (double)Tn);
    out[GTEC * 2]     = (float)aux;
    out[GTEC * 2 + 1] = (float)zloss;
  }
}

// ---------------------------------------------------------------------------
// k6: single-pass output writer. One block per token: zero-fill its [E,C]
// slab in dispatch + combine and insert the <=2 nonzeros. float4 coalesced.
// ---------------------------------------------------------------------------
__global__ __launch_bounds__(256) void k6_fill(
    const int* __restrict__ idx0, const int* __restrict__ idx1,
    const int* __restrict__ prio0, const int* __restrict__ prio1,
    const float* __restrict__ g0f, const float* __restrict__ g1f,
    float* __restrict__ out)
{
  const size_t gt = (size_t)blockIdx.x;            // 0..GT-1
  const int tid = threadIdx.x;
  const int e0 = idx0[gt], e1 = idx1[gt];
  const int p0 = prio0[gt], p1 = prio1[gt];
  const float v0 = g0f[gt], v1 = g1f[gt];
  const int n0 = (p0 < CAPn) ? e0 * CAPn + p0 : -1;
  const int n1 = (p1 < CAPn) ? e1 * CAPn + p1 : -1;
  const int q0 = n0 >> 2, q1 = n1 >> 2;            // -1 stays negative
  float4* disp = (float4*)(out + gt * (size_t)(En * CAPn));
  float4* comb = (float4*)(out + GTEC + gt * (size_t)(En * CAPn));
  #pragma unroll
  for (int i = 0; i < 8; ++i) {
    int q = tid + 256 * i;                         // 2048 float4 per array
    float4 v = {0.f, 0.f, 0.f, 0.f};
    float4 w = {0.f, 0.f, 0.f, 0.f};
    if (q == q0) { ((float*)&v)[n0 & 3] = 1.0f; ((float*)&w)[n0 & 3] = v0; }
    if (q == q1) { ((float*)&v)[n1 & 3] = 1.0f; ((float*)&w)[n1 & 3] = v1; }
    disp[q] = v;
    comb[q] = w;
  }
}

// ---------------------------------------------------------------------------
extern "C" void kernel_launch(void* const* d_in, const int* in_sizes, int n_in,
                              void* d_out, int out_size, void* d_ws, size_t ws_size,
                              hipStream_t stream)
{
  (void)in_sizes; (void)n_in; (void)out_size; (void)ws_size;
  const float* X  = (const float*)d_in[0];   // [G,T,H]
  const float* W  = (const float*)d_in[1];   // [H,E]
  const float* Bv = (const float*)d_in[2];   // [E]
  float* out = (float*)d_out;

  char* ws = (char*)d_ws;
  size_t off = 0;
  auto carve = [&](size_t bytes) -> void* {
    void* p = ws + off;
    off += (bytes + 255) & ~(size_t)255;
    return p;
  };
  double* dkey   = (double*)carve(GT * 8);
  double* dlogz2 = (double*)carve(GT * 8);
  double* sumpr  = (double*)carve((size_t)Gn * En * 8);
  float*  probs  = (float*) carve(GT * En * 4);
  int* idx0  = (int*)carve(GT * 4);
  int* idx1  = (int*)carve(GT * 4);
  float* g0f = (float*)carve(GT * 4);
  float* g1f = (float*)carve(GT * 4);
  int* perm  = (int*)carve(GT * 4);
  int* sidx0 = (int*)carve(GT * 4);
  int* sidx1 = (int*)carve(GT * 4);
  int* prio0 = (int*)carve(GT * 4);
  int* prio1 = (int*)carve(GT * 4);
  int* cntge = (int*)carve((size_t)Gn * En * 4);

  k1_gemm<<<Gn * Tn / 8, 256, 0, stream>>>(X, W, Bv, dkey, dlogz2, probs,
                                           idx0, idx1, g0f, g1f);
  k2_rank<<<Gn * 16, 256, 0, stream>>>(dkey, idx0, idx1, perm, sidx0, sidx1);
  k3_prio<<<(Gn * En) / 4, 256, 0, stream>>>(sidx0, sidx1, perm, prio0, prio1, cntge);
  k4_sumprob<<<(Gn * En) / 4, 256, 0, stream>>>(probs, sumpr);
  k5_scalars<<<1, 256, 0, stream>>>(dlogz2, sumpr, cntge, out);
  k6_fill<<<(int)GT, 256, 0, stream>>>(idx0, idx1, prio0, prio1, g0f, g1f, out);
}

// Round 3
// 467.329 us; speedup vs baseline: 1.3939x; 1.3939x over previous
//
#include <hip/hip_runtime.h>
#include <cstdint>
#include <cstddef>

static constexpr int Gn = 2;
static constexpr int Tn = 4096;
static constexpr int Hn = 2048;
static constexpr int En = 64;
static constexpr int CAPn = 128;
static constexpr size_t GT = (size_t)Gn * Tn;          // 8192
static constexpr size_t GTEC = GT * En * CAPn;         // 67,108,864

// ---------------------------------------------------------------------------
// Wave-level (64 lanes = 64 experts) softmax + top-2 + z-loss term, all f64.
// Tie-breaking on equal probs: lower expert index wins (matches lax.top_k).
// ---------------------------------------------------------------------------
__device__ inline void wave_softmax_topk(
    double logit, int g, int t,
    double* __restrict__ dkey, double* __restrict__ dlogz2,
    float* __restrict__ probs,
    int* __restrict__ idx0, int* __restrict__ idx1,
    float* __restrict__ g0f, float* __restrict__ g1f)
{
  const int e = threadIdx.x & 63;
  double m = logit;
  #pragma unroll
  for (int off = 32; off; off >>= 1) {
    double o = __shfl_xor(m, off);
    m = o > m ? o : m;
  }
  double ex = exp(logit - m);
  double s = ex;
  #pragma unroll
  for (int off = 32; off; off >>= 1) s += __shfl_xor(s, off);
  double p = ex / s;
  size_t gt = (size_t)g * Tn + t;
  probs[gt * En + e] = (float)p;

  // top-1 (value, index) with lower-index tie-break
  double bp = p; int bi = e;
  #pragma unroll
  for (int off = 32; off; off >>= 1) {
    double op = __shfl_xor(bp, off);
    int    oi = __shfl_xor(bi, off);
    if (op > bp || (op == bp && oi < bi)) { bp = op; bi = oi; }
  }
  // top-2: mask out top-1 lane
  double q = (e == bi) ? -1.0 : p;
  double bp2 = q; int bi2 = e;
  #pragma unroll
  for (int off = 32; off; off >>= 1) {
    double op = __shfl_xor(bp2, off);
    int    oi = __shfl_xor(bi2, off);
    if (op > bp2 || (op == bp2 && oi < bi2)) { bp2 = op; bi2 = oi; }
  }
  if (e == 0) {
    dkey[gt] = bp;                       // sort key = top-1 gate (f64)
    double lz = m + log(s);              // logsumexp
    dlogz2[gt] = lz * lz;
    idx0[gt] = bi;  idx1[gt] = bi2;
    g0f[gt] = (float)bp;  g1f[gt] = (float)bp2;
  }
}

// ---------------------------------------------------------------------------
// k0: convert W (f32 [H,E]) -> W64 (f64) once. Removes per-FMA cvt in k1.
// ---------------------------------------------------------------------------
__global__ __launch_bounds__(256) void k0_wcvt(
    const float* __restrict__ W, double* __restrict__ W64)
{
  int i = blockIdx.x * 256 + threadIdx.x;   // Hn*En = 131072 elements
  if (i < Hn * En) W64[i] = (double)W[i];
}

// ---------------------------------------------------------------------------
// k1: logits + softmax + top2. 16 tokens/block, 256 thr (4 waves).
// lane = expert. Wave w owns tokens [4w,4w+4) and accumulates h=0..2047
// STRICTLY SEQUENTIALLY (chunks in order, hh in order) — bit-identical f64
// order to the validated R1 kernel, so all discrete decisions reproduce.
// x is staged per 512-h chunk into LDS as f64 (converted once, coalesced).
// Per K-step: 1 coalesced W64 load + 4 broadcast LDS reads + 4 f64 FMAs.
// ---------------------------------------------------------------------------
__global__ __launch_bounds__(256) void k1_gemm(
    const float* __restrict__ X, const double* __restrict__ W64,
    const float* __restrict__ Bv,
    double* __restrict__ dkey, double* __restrict__ dlogz2,
    float* __restrict__ probs,
    int* __restrict__ idx0, int* __restrict__ idx1,
    float* __restrict__ g0f, float* __restrict__ g1f)
{
  __shared__ double xs[16][512];                   // 64 KB (one h-chunk)
  const int tid  = threadIdx.x;
  const int bid  = blockIdx.x;
  const int g    = bid >> 8;                       // 256 blocks per group
  const int t0   = (bid & 255) * 16;
  const int lane = tid & 63;
  const int w    = tid >> 6;                       // wave 0..3

  double acc[4];
  #pragma unroll
  for (int q = 0; q < 4; ++q) acc[q] = 0.0;

  const size_t xbase = ((size_t)g * Tn + t0) * Hn;

  for (int c = 0; c < 4; ++c) {
    __syncthreads();                               // xs free to overwrite
    // stage chunk c: 16 tokens x 512 h floats -> f64 LDS (coalesced reads)
    // 16*512 floats = 2048 float4 = 8 reps of 256 threads
    #pragma unroll
    for (int rep = 0; rep < 8; ++rep) {
      int flat = rep * 256 + tid;                  // [0,2048) float4 units
      int j  = flat >> 7;                          // 128 float4 per token row
      int c4 = flat & 127;
      float4 v = *(const float4*)(X + xbase + (size_t)j * Hn + c * 512 + c4 * 4);
      double2* dst = (double2*)&xs[j][c4 * 4];
      dst[0] = make_double2((double)v.x, (double)v.y);
      dst[1] = make_double2((double)v.z, (double)v.w);
    }
    __syncthreads();
    // compute: wave w handles tokens 4w..4w+3 over ALL 512 h of this chunk,
    // in sequential h order (preserves f64 accumulation order).
    const double* wp = W64 + (size_t)(c * 512) * En + lane;
    const double* x0 = xs[w * 4 + 0];
    const double* x1 = xs[w * 4 + 1];
    const double* x2 = xs[w * 4 + 2];
    const double* x3 = xs[w * 4 + 3];
    #pragma unroll 4
    for (int hh = 0; hh < 512; ++hh) {
      double wv = wp[(size_t)hh * En];
      acc[0] += x0[hh] * wv;
      acc[1] += x1[hh] * wv;
      acc[2] += x2[hh] * wv;
      acc[3] += x3[hh] * wv;
    }
  }

  const double bv = (double)Bv[lane];
  #pragma unroll
  for (int q = 0; q < 4; ++q) {
    wave_softmax_topk(acc[q] + bv, g, t0 + w * 4 + q,
                      dkey, dlogz2, probs, idx0, idx1, g0f, g1f);
  }
}

// ---------------------------------------------------------------------------
// k2: stable descending rank (== argsort(-gate0, stable)). O(T^2) compares,
// keys broadcast from LDS. Scatters perm + expert ids into sorted order.
// ---------------------------------------------------------------------------
__global__ __launch_bounds__(256) void k2_rank(
    const double* __restrict__ dkey,
    const int* __restrict__ idx0, const int* __restrict__ idx1,
    int* __restrict__ perm, int* __restrict__ sidx0, int* __restrict__ sidx1)
{
  __shared__ double keys[Tn];                      // 32 KB
  const int tid = threadIdx.x;
  const int bid = blockIdx.x;
  const int g = bid >> 4;                          // 16 blocks per group
  const int part = bid & 15;
  const size_t gbase = (size_t)g * Tn;
  for (int i = tid; i < Tn; i += 256) keys[i] = dkey[gbase + i];
  __syncthreads();

  const int tg = part * 256 + tid;
  const double k = keys[tg];
  int r = 0;
  for (int j = 0; j < Tn; ++j) {
    double kj = keys[j];
    r += (kj > k) || (kj == k && j < tg);          // stable, descending
  }
  perm[gbase + r]  = tg;
  sidx0[gbase + r] = idx0[gbase + tg];
  sidx1[gbase + r] = idx1[gbase + tg];
}

// ---------------------------------------------------------------------------
// k3: exact cumsum priorities. One wave per (g,e); scan sorted k=0 stream,
// then k=1 stream (flat order k*T + p), via ballot + popcount prefix.
// ---------------------------------------------------------------------------
__global__ __launch_bounds__(256) void k3_prio(
    const int* __restrict__ sidx0, const int* __restrict__ sidx1,
    const int* __restrict__ perm,
    int* __restrict__ prio0, int* __restrict__ prio1, int* __restrict__ cntge)
{
  const int tid  = threadIdx.x;
  const int wid  = (blockIdx.x * 256 + tid) >> 6;  // 0..127 = (g,e)
  const int lane = tid & 63;
  const int g = wid >> 6, e = wid & 63;
  const size_t gbase = (size_t)g * Tn;
  int cnt = 0;
  for (int step = 0; step < Tn / 64; ++step) {
    int p = step * 64 + lane;
    bool mt = (sidx0[gbase + p] == e);
    unsigned long long mask = __ballot(mt);
    int pr = cnt + __popcll(mask & ((1ull << lane) - 1ull));
    if (mt) prio0[gbase + perm[gbase + p]] = pr;
    cnt += __popcll(mask);
  }
  for (int step = 0; step < Tn / 64; ++step) {
    int p = step * 64 + lane;
    bool mt = (sidx1[gbase + p] == e);
    unsigned long long mask = __ballot(mt);
    int pr = cnt + __popcll(mask & ((1ull << lane) - 1ull));
    if (mt) prio1[gbase + perm[gbase + p]] = pr;
    cnt += __popcll(mask);
  }
  if (lane == 0) cntge[g * En + e] = cnt;          // tokens routed to (g,e)
}

// ---------------------------------------------------------------------------
// k4: per-(g,e) probability sums (deterministic: fixed lane strides + tree).
// ---------------------------------------------------------------------------
__global__ __launch_bounds__(256) void k4_sumprob(
    const float* __restrict__ probs, double* __restrict__ sumprob)
{
  const int tid  = threadIdx.x;
  const int wid  = (blockIdx.x * 256 + tid) >> 6;
  const int lane = tid & 63;
  const int g = wid >> 6, e = wid & 63;
  double s = 0.0;
  for (int i = 0; i < Tn / 64; ++i) {
    int t = i * 64 + lane;
    s += (double)probs[((size_t)g * Tn + t) * En + e];
  }
  #pragma unroll
  for (int off = 32; off; off >>= 1) s += __shfl_xor(s, off);
  if (lane == 0) sumprob[g * En + e] = s;
}

// ---------------------------------------------------------------------------
// k5: scalar losses (deterministic LDS tree reductions).
// ---------------------------------------------------------------------------
__global__ __launch_bounds__(256) void k5_scalars(
    const double* __restrict__ dlogz2, const double* __restrict__ sumprob,
    const int* __restrict__ cntge, float* __restrict__ out)
{
  __shared__ double red[256];
  const int tid = threadIdx.x;
  double z = 0.0;
  for (int i = tid; i < (int)GT; i += 256) z += dlogz2[i];
  red[tid] = z; __syncthreads();
  for (int s = 128; s; s >>= 1) { if (tid < s) red[tid] += red[tid + s]; __syncthreads(); }
  double zloss = red[0] / (double)GT;
  __syncthreads();

  double a = 0.0;
  if (tid < Gn * En) a = (double)cntge[tid] * sumprob[tid];
  red[tid] = a; __syncthreads();
  for (int s = 128; s; s >>= 1) { if (tid < s) red[tid] += red[tid + s]; __syncthreads(); }
  if (tid == 0) {
    // mean_{g,e}((cnt/T)*(sp/T)) * E^2  =  sum(cnt*sp) * E / (G*T*T)
    double aux = red[0] * (double)En / ((double)Gn * (double)Tn * (double)Tn);
    out[GTEC * 2]     = (float)aux;
    out[GTEC * 2 + 1] = (float)zloss;
  }
}

// ---------------------------------------------------------------------------
// k6: single-pass output writer. One block per token: zero-fill its [E,C]
// slab in dispatch + combine and insert the <=2 nonzeros. float4 coalesced.
// ---------------------------------------------------------------------------
__global__ __launch_bounds__(256) void k6_fill(
    const int* __restrict__ idx0, const int* __restrict__ idx1,
    const int* __restrict__ prio0, const int* __restrict__ prio1,
    const float* __restrict__ g0f, const float* __restrict__ g1f,
    float* __restrict__ out)
{
  const size_t gt = (size_t)blockIdx.x;            // 0..GT-1
  const int tid = threadIdx.x;
  const int e0 = idx0[gt], e1 = idx1[gt];
  const int p0 = prio0[gt], p1 = prio1[gt];
  const float v0 = g0f[gt], v1 = g1f[gt];
  const int n0 = (p0 < CAPn) ? e0 * CAPn + p0 : -1;
  const int n1 = (p1 < CAPn) ? e1 * CAPn + p1 : -1;
  const int q0 = n0 >> 2, q1 = n1 >> 2;            // -1 stays negative
  float4* disp = (float4*)(out + gt * (size_t)(En * CAPn));
  float4* comb = (float4*)(out + GTEC + gt * (size_t)(En * CAPn));
  #pragma unroll
  for (int i = 0; i < 8; ++i) {
    int q = tid + 256 * i;                         // 2048 float4 per array
    float4 v = {0.f, 0.f, 0.f, 0.f};
    float4 w = {0.f, 0.f, 0.f, 0.f};
    if (q == q0) { ((float*)&v)[n0 & 3] = 1.0f; ((float*)&w)[n0 & 3] = v0; }
    if (q == q1) { ((float*)&v)[n1 & 3] = 1.0f; ((float*)&w)[n1 & 3] = v1; }
    disp[q] = v;
    comb[q] = w;
  }
}

// ---------------------------------------------------------------------------
extern "C" void kernel_launch(void* const* d_in, const int* in_sizes, int n_in,
                              void* d_out, int out_size, void* d_ws, size_t ws_size,
                              hipStream_t stream)
{
  (void)in_sizes; (void)n_in; (void)out_size; (void)ws_size;
  const float* X  = (const float*)d_in[0];   // [G,T,H]
  const float* W  = (const float*)d_in[1];   // [H,E]
  const float* Bv = (const float*)d_in[2];   // [E]
  float* out = (float*)d_out;

  char* ws = (char*)d_ws;
  size_t off = 0;
  auto carve = [&](size_t bytes) -> void* {
    void* p = ws + off;
    off += (bytes + 255) & ~(size_t)255;
    return p;
  };
  double* W64    = (double*)carve((size_t)Hn * En * 8);   // 1 MB
  double* dkey   = (double*)carve(GT * 8);
  double* dlogz2 = (double*)carve(GT * 8);
  double* sumpr  = (double*)carve((size_t)Gn * En * 8);
  float*  probs  = (float*) carve(GT * En * 4);
  int* idx0  = (int*)carve(GT * 4);
  int* idx1  = (int*)carve(GT * 4);
  float* g0f = (float*)carve(GT * 4);
  float* g1f = (float*)carve(GT * 4);
  int* perm  = (int*)carve(GT * 4);
  int* sidx0 = (int*)carve(GT * 4);
  int* sidx1 = (int*)carve(GT * 4);
  int* prio0 = (int*)carve(GT * 4);
  int* prio1 = (int*)carve(GT * 4);
  int* cntge = (int*)carve((size_t)Gn * En * 4);

  k0_wcvt<<<(Hn * En + 255) / 256, 256, 0, stream>>>(W, W64);
  k1_gemm<<<Gn * Tn / 16, 256, 0, stream>>>(X, W64, Bv, dkey, dlogz2, probs,
                                            idx0, idx1, g0f, g1f);
  k2_rank<<<Gn * 16, 256, 0, stream>>>(dkey, idx0, idx1, perm, sidx0, sidx1);
  k3_prio<<<(Gn * En) / 4, 256, 0, stream>>>(sidx0, sidx1, perm, prio0, prio1, cntge);
  k4_sumprob<<<(Gn * En) / 4, 256, 0, stream>>>(probs, sumpr);
  k5_scalars<<<1, 256, 0, stream>>>(dlogz2, sumpr, cntge, out);
  k6_fill<<<(int)GT, 256, 0, stream>>>(idx0, idx1, prio0, prio1, g0f, g1f, out);
}